// Round 1
// 1329.888 us; speedup vs baseline: 1.0098x; 1.0098x over previous
//
#include <hip/hip_runtime.h>
#include <hip/hip_bf16.h>

// TGCN graph convolution: out = (L @ [inputs|hidden]) @ W + b
// N=16384, B=2, F=32, G=16, OUT=16.  Dominant cost: stream L (1.07 GB fp32).
// v2: double-buffered LDS + counted s_waitcnt vmcnt(7) (T3+T4) so next-tile
// global_load_lds stays in flight across barriers -> HBM never drains.
// SPLITK=2 (512 blocks = exactly 2/CU resident), bijective XCD swizzle so
// each XCD's 64 blocks share one 1.5 MB B-panel in its private L2.
// Workspace: Xt bf16 3 MB @ ws+0, Cp fp32 partials 12.6 MB @ ws+4MB.

#define NN   16384
#define FF   32
#define GG   16
#define OUTD 16
#define C96  96
#define BM   64
#define BK   64
#define SPLITK 2
#define KCHUNK (NN / SPLITK)    // 8192
#define KITERS (KCHUNK / BK)    // 128

typedef __attribute__((ext_vector_type(8))) short short8;
typedef __attribute__((ext_vector_type(4))) float f32x4;

using as1_void = __attribute__((address_space(1))) void;
using as3_void = __attribute__((address_space(3))) void;

__device__ __forceinline__ unsigned short f2bf(float f) {
  __hip_bfloat16 h = __float2bfloat16(f);
  return __builtin_bit_cast(unsigned short, h);
}

// raw workgroup barrier WITHOUT the vmcnt(0) drain __syncthreads() emits;
// memory-clobber asm pins IR-level motion of LDS/global ops on both sides.
__device__ __forceinline__ void wg_barrier() {
  asm volatile("" ::: "memory");
  __builtin_amdgcn_s_barrier();
  asm volatile("" ::: "memory");
}

// ---------------------------------------------------------------------------
// Prep: Xt[c][n] bf16, c = b*48 + (f | 32+g), via LDS transpose (coalesced).
// ---------------------------------------------------------------------------
__global__ __launch_bounds__(256) void prep_xt(const float* __restrict__ inp,
                                               const float* __restrict__ hid,
                                               unsigned short* __restrict__ xt) {
  __shared__ float lds_cat[C96][64];
  const int tid = threadIdx.x;
  const int n0 = blockIdx.x * 64;

  // inputs: per batch 64 nodes x 32 f = 512 float4
#pragma unroll
  for (int r = 0; r < 2; ++r) {
    int fi = tid + r * 256;       // 0..511
    int n = fi >> 3;
    int f4 = fi & 7;
#pragma unroll
    for (int b = 0; b < 2; ++b) {
      const float4* src = (const float4*)(inp + ((size_t)b * NN + (n0 + n)) * FF) + f4;
      float4 v = *src;
      int c = b * 48 + f4 * 4;
      lds_cat[c + 0][n] = v.x;
      lds_cat[c + 1][n] = v.y;
      lds_cat[c + 2][n] = v.z;
      lds_cat[c + 3][n] = v.w;
    }
  }
  // hidden: per batch 64 nodes x 16 g = 256 float4
  {
    int n = tid >> 2;
    int g4 = tid & 3;
#pragma unroll
    for (int b = 0; b < 2; ++b) {
      const float4* src = (const float4*)(hid + ((size_t)b * NN + (n0 + n)) * GG) + g4;
      float4 v = *src;
      int c = b * 48 + 32 + g4 * 4;
      lds_cat[c + 0][n] = v.x;
      lds_cat[c + 1][n] = v.y;
      lds_cat[c + 2][n] = v.z;
      lds_cat[c + 3][n] = v.w;
    }
  }
  __syncthreads();
  // write Xt rows: 768 16B-units, 3 per thread, coalesced along n
#pragma unroll
  for (int r = 0; r < 3; ++r) {
    int u = tid + r * 256;
    int c = u >> 3;
    int nn = (u & 7) * 8;
    short8 o;
#pragma unroll
    for (int j = 0; j < 8; ++j) o[j] = (short)f2bf(lds_cat[c][nn + j]);
    *(short8*)(xt + (size_t)c * NN + n0 + nn) = o;
  }
}

// ---------------------------------------------------------------------------
// Main: Cp[split][m][c96] = partial L @ X over this block's K range.
// A tile 64x64 fp32 (16 KB), B tile 96x64 bf16 (12 KB), DOUBLE-buffered
// (56 KB LDS -> 2 blocks/CU). XOR swizzle baked into per-lane GLOBAL src of
// global_load_lds (LDS fills linearly, lands swizzled):
//   A unit (row,cu4) at slot row*16 + (cu4 ^ (row&15));
//   B unit (c,kg8)  at slot c*8   + (kg8 ^ (c&7)).
// Pipeline per iter: stage(next buf) -> vmcnt(7) [wait PREV tile only] ->
// barrier -> compute(cur) -> barrier.  Next tile's 7 loads/thread remain in
// flight through compute, so HBM stays saturated (no vmcnt(0) drain).
// ---------------------------------------------------------------------------
__global__ __launch_bounds__(256, 2) void spmm_main(const float* __restrict__ L,
                                                    const unsigned short* __restrict__ xt,
                                                    float* __restrict__ cp) {
  __shared__ __align__(16) float lds_a[2][BM * BK];            // 2 x 16 KB
  __shared__ __align__(16) unsigned short lds_b[2][C96 * BK];  // 2 x 12 KB

  const int tid = threadIdx.x;
  const int wave = tid >> 6;
  const int lane = tid & 63;

  // Bijective XCD remap: 512 wgs round-robin XCDs by (wg&7); give each XCD a
  // contiguous chunk so its 64 blocks share one split-K B panel in its L2.
  const int wg = blockIdx.x;
  const int swz = (wg & 7) * (512 / 8) + (wg >> 3);   // [0,512) bijective
  const int my = swz >> 8;                            // split-K index 0..1
  const int mx = swz & 255;                           // m-block 0..255
  const int m0 = mx * BM;
  const int kbase = my * KCHUNK;

  // staging source/dest (k0-invariant parts)
  const float* asrc[4];
  int adst[4];   // float offset within one A buffer (wave-uniform)
#pragma unroll
  for (int a = 0; a < 4; ++a) {
    int s = wave * 256 + a * 64 + lane;
    int row = s >> 4;
    int cu = (s & 15) ^ (row & 15);
    asrc[a] = L + (size_t)(m0 + row) * NN + kbase + cu * 4;
    adst[a] = (wave * 256 + a * 64) * 4;
  }
  const unsigned short* bsrc[3];
  int bdst[3];   // short offset within one B buffer (wave-uniform)
#pragma unroll
  for (int bi = 0; bi < 3; ++bi) {
    int s = wave * 192 + bi * 64 + lane;
    int c = s >> 3;
    int kg = (s & 7) ^ (c & 7);
    bsrc[bi] = xt + (size_t)c * NN + kbase + kg * 8;
    bdst[bi] = (wave * 192 + bi * 64) * 8;
  }

  // fragment LDS offsets (iteration-invariant)
  const int rowA = wave * 16 + (lane & 15);
  const int lq = lane >> 4;
  int aoff[2][2];
#pragma unroll
  for (int kk = 0; kk < 2; ++kk) {
    int cu0 = kk * 8 + lq * 2;
    aoff[kk][0] = (rowA * 16 + (cu0 ^ (rowA & 15))) * 4;
    aoff[kk][1] = (rowA * 16 + ((cu0 + 1) ^ (rowA & 15))) * 4;
  }
  int boff[2][6];
#pragma unroll
  for (int kk = 0; kk < 2; ++kk)
#pragma unroll
    for (int t = 0; t < 6; ++t) {
      int c = t * 16 + (lane & 15);
      int kg = kk * 4 + lq;
      boff[kk][t] = (c * 8 + (kg ^ (c & 7))) * 8;
    }

  f32x4 acc[6];
#pragma unroll
  for (int t = 0; t < 6; ++t) acc[t] = (f32x4){0.f, 0.f, 0.f, 0.f};

  auto stage = [&](int buf, int ko) {
#pragma unroll
    for (int a = 0; a < 4; ++a)
      __builtin_amdgcn_global_load_lds((const as1_void*)(asrc[a] + ko),
                                       (as3_void*)(&lds_a[buf][adst[a]]), 16, 0, 0);
#pragma unroll
    for (int bi = 0; bi < 3; ++bi)
      __builtin_amdgcn_global_load_lds((const as1_void*)(bsrc[bi] + ko),
                                       (as3_void*)(&lds_b[buf][bdst[bi]]), 16, 0, 0);
  };

  auto compute = [&](int buf) {
#pragma unroll
    for (int kk = 0; kk < 2; ++kk) {
      f32x4 a0 = *(const f32x4*)(&lds_a[buf][aoff[kk][0]]);
      f32x4 a1 = *(const f32x4*)(&lds_a[buf][aoff[kk][1]]);
      short8 af;
      af[0] = (short)f2bf(a0[0]);
      af[1] = (short)f2bf(a0[1]);
      af[2] = (short)f2bf(a0[2]);
      af[3] = (short)f2bf(a0[3]);
      af[4] = (short)f2bf(a1[0]);
      af[5] = (short)f2bf(a1[1]);
      af[6] = (short)f2bf(a1[2]);
      af[7] = (short)f2bf(a1[3]);
#pragma unroll
      for (int t = 0; t < 6; ++t) {
        short8 bf = *(const short8*)(&lds_b[buf][boff[kk][t]]);
        acc[t] = __builtin_amdgcn_mfma_f32_16x16x32_bf16(af, bf, acc[t], 0, 0, 0);
      }
    }
  };

  // prologue: fill buffer 0 with tile 0 (7 loads/thread in flight)
  stage(0, 0);
  int cur = 0;
  for (int it = 0; it < KITERS - 1; ++it) {
    stage(cur ^ 1, (it + 1) * BK);                    // issue next tile (7 more)
    asm volatile("s_waitcnt vmcnt(7)" ::: "memory");  // wait CUR tile only
    __builtin_amdgcn_s_barrier();                     // all waves' cur complete
    asm volatile("" ::: "memory");
    compute(cur);
    wg_barrier();                                     // done reading cur buffer
    cur ^= 1;
  }
  asm volatile("s_waitcnt vmcnt(0)" ::: "memory");    // last tile
  __builtin_amdgcn_s_barrier();
  asm volatile("" ::: "memory");
  compute(cur);

  // store split-K partial tile (each region written exactly once)
  float* cpd = cp + ((size_t)my * NN + m0) * C96;
#pragma unroll
  for (int t = 0; t < 6; ++t) {
    int col = t * 16 + (lane & 15);
#pragma unroll
    for (int r = 0; r < 4; ++r) {
      int row = wave * 16 + lq * 4 + r;
      cpd[(size_t)row * C96 + col] = acc[t][r];
    }
  }
}

// ---------------------------------------------------------------------------
// Epilogue: sum split-K partials, apply W[48x16] + bias, write out[2][N][16].
// ---------------------------------------------------------------------------
__global__ __launch_bounds__(256) void epilogue(const float* __restrict__ cp,
                                                const float* __restrict__ w,
                                                const float* __restrict__ bias,
                                                float* __restrict__ out) {
  __shared__ float lds_c[64 * 97];   // 64 nodes x 96 cols, +1 pad per row
  __shared__ float lds_w[48 * 16];
  __shared__ float lds_bias[16];
  const int tid = threadIdx.x;
  const int n0 = blockIdx.x * 64;

  for (int i = tid; i < 768; i += 256) lds_w[i] = w[i];
  if (tid < 16) lds_bias[tid] = bias[tid];

  const size_t base = (size_t)n0 * C96;
#pragma unroll
  for (int i = 0; i < 24; ++i) {
    int e = tid + i * 256;   // 0..6143 over [64 x 96]
    float s = 0.f;
#pragma unroll
    for (int sp = 0; sp < SPLITK; ++sp)
      s += cp[(size_t)sp * (NN * C96) + base + e];
    lds_c[e + e / 96] = s;   // node*97 + col
  }
  __syncthreads();

  const int node = tid >> 2;
  const int b = (tid >> 1) & 1;
  const int o0 = (tid & 1) * 8;
  const float* crow = &lds_c[node * 97 + b * 48];
  float accv[8];
#pragma unroll
  for (int o = 0; o < 8; ++o) accv[o] = lds_bias[o0 + o];
#pragma unroll
  for (int j = 0; j < 48; ++j) {
    float cv = crow[j];
#pragma unroll
    for (int o = 0; o < 8; ++o) accv[o] += cv * lds_w[j * 16 + o0 + o];
  }
  size_t ob = (size_t)b * (NN * OUTD) + (size_t)(n0 + node) * OUTD + o0;
  float4 v0 = {accv[0], accv[1], accv[2], accv[3]};
  float4 v1 = {accv[4], accv[5], accv[6], accv[7]};
  *(float4*)(out + ob) = v0;
  *(float4*)(out + ob + 4) = v1;
}

extern "C" void kernel_launch(void* const* d_in, const int* in_sizes, int n_in,
                              void* d_out, int out_size, void* d_ws, size_t ws_size,
                              hipStream_t stream) {
  (void)in_sizes; (void)n_in; (void)out_size; (void)ws_size;
  const float* inp = (const float*)d_in[0];   // [2,16384,32]
  const float* hid = (const float*)d_in[1];   // [2,16384*16]
  const float* lap = (const float*)d_in[2];   // [16384,16384]
  const float* wts = (const float*)d_in[3];   // [48,16]
  const float* bia = (const float*)d_in[4];   // [16]
  float* out = (float*)d_out;                 // [2,16384*16]

  unsigned short* xt = (unsigned short*)d_ws;                  // 3 MB bf16
  float* cp = (float*)((char*)d_ws + (4u << 20));              // 12.6 MB fp32

  prep_xt<<<NN / 64, 256, 0, stream>>>(inp, hid, xt);
  spmm_main<<<dim3(NN / BM * SPLITK), 256, 0, stream>>>(lap, xt, cp);
  epilogue<<<NN / 64, 256, 0, stream>>>(cp, wts, bia, out);
}

// Round 2
// 1329.499 us; speedup vs baseline: 1.0101x; 1.0003x over previous
//
#include <hip/hip_runtime.h>
#include <hip/hip_bf16.h>

// TGCN graph convolution: out = (L @ [inputs|hidden]) @ W + b
// N=16384, B=2, F=32, G=16, OUT=16.  Dominant cost: stream L (1.07 GB fp32).
// v3: defeat compiler-inserted vmcnt(0) drains.  v2's counted-vmcnt pipeline
// was nullified because C++ LDS reads of lds[buf] (runtime buf) alias the
// in-flight global_load_lds writes -> waitcnt pass inserts vmcnt(0) per iter.
// Now: 4 distinct __shared__ objects, loop unrolled x2 (compile-time buffer
// identity), and ALL fragment reads via inline-asm ds_read_b128 (invisible to
// the waitcnt pass).  Sync is fully manual: vmcnt(7) -> barrier -> asm reads
// -> lgkmcnt(0)+sched_barrier (rule #18) -> barrier -> stage(t+2) -> MFMA.
// 14 DMA instructions (2 tiles) stay in flight through every compute phase.
// Workspace: Xt bf16 3 MB @ ws+0, Cp fp32 partials 12.6 MB @ ws+4MB.

#define NN   16384
#define FF   32
#define GG   16
#define OUTD 16
#define C96  96
#define BM   64
#define BK   64
#define SPLITK 2
#define KCHUNK (NN / SPLITK)    // 8192
#define KITERS (KCHUNK / BK)    // 128

typedef __attribute__((ext_vector_type(8))) short short8;
typedef __attribute__((ext_vector_type(4))) float f32x4;

using as1_void = __attribute__((address_space(1))) void;
using as3_void = __attribute__((address_space(3))) void;

__device__ __forceinline__ unsigned short f2bf(float f) {
  __hip_bfloat16 h = __float2bfloat16(f);
  return __builtin_bit_cast(unsigned short, h);
}

__device__ __forceinline__ unsigned lds_off(const void* p) {
  // generic -> AS3 (strips aperture) -> 32-bit LDS byte offset
  return (unsigned)(uintptr_t)(as3_void*)p;
}

__device__ __forceinline__ f32x4 ds_read128f(unsigned addr) {
  f32x4 r;
  asm volatile("ds_read_b128 %0, %1" : "=v"(r) : "v"(addr));
  return r;
}
__device__ __forceinline__ short8 ds_read128s(unsigned addr) {
  short8 r;
  asm volatile("ds_read_b128 %0, %1" : "=v"(r) : "v"(addr));
  return r;
}

// ---------------------------------------------------------------------------
// Prep: Xt[c][n] bf16, c = b*48 + (f | 32+g), via LDS transpose (coalesced).
// ---------------------------------------------------------------------------
__global__ __launch_bounds__(256) void prep_xt(const float* __restrict__ inp,
                                               const float* __restrict__ hid,
                                               unsigned short* __restrict__ xt) {
  __shared__ float lds_cat[C96][64];
  const int tid = threadIdx.x;
  const int n0 = blockIdx.x * 64;

#pragma unroll
  for (int r = 0; r < 2; ++r) {
    int fi = tid + r * 256;       // 0..511
    int n = fi >> 3;
    int f4 = fi & 7;
#pragma unroll
    for (int b = 0; b < 2; ++b) {
      const float4* src = (const float4*)(inp + ((size_t)b * NN + (n0 + n)) * FF) + f4;
      float4 v = *src;
      int c = b * 48 + f4 * 4;
      lds_cat[c + 0][n] = v.x;
      lds_cat[c + 1][n] = v.y;
      lds_cat[c + 2][n] = v.z;
      lds_cat[c + 3][n] = v.w;
    }
  }
  {
    int n = tid >> 2;
    int g4 = tid & 3;
#pragma unroll
    for (int b = 0; b < 2; ++b) {
      const float4* src = (const float4*)(hid + ((size_t)b * NN + (n0 + n)) * GG) + g4;
      float4 v = *src;
      int c = b * 48 + 32 + g4 * 4;
      lds_cat[c + 0][n] = v.x;
      lds_cat[c + 1][n] = v.y;
      lds_cat[c + 2][n] = v.z;
      lds_cat[c + 3][n] = v.w;
    }
  }
  __syncthreads();
#pragma unroll
  for (int r = 0; r < 3; ++r) {
    int u = tid + r * 256;
    int c = u >> 3;
    int nn = (u & 7) * 8;
    short8 o;
#pragma unroll
    for (int j = 0; j < 8; ++j) o[j] = (short)f2bf(lds_cat[c][nn + j]);
    *(short8*)(xt + (size_t)c * NN + n0 + nn) = o;
  }
}

// ---------------------------------------------------------------------------
// Main: Cp[split][m][c96] = partial L @ X over this block's K range.
// A tile 64x64 fp32 (16 KB), B tile 96x64 bf16 (12 KB), double-buffered as
// FOUR distinct __shared__ objects (a0,a1,b0,b1) so LDS-DMA alias analysis
// can distinguish them.  XOR swizzle baked into per-lane GLOBAL src of
// global_load_lds (LDS fills linearly, lands swizzled):
//   A unit (row,cu4) at slot row*16 + (cu4 ^ (row&15));
//   B unit (c,kg8)  at slot c*8   + (kg8 ^ (c&7)).
// ---------------------------------------------------------------------------
__global__ __launch_bounds__(256, 2) void spmm_main(const float* __restrict__ L,
                                                    const unsigned short* __restrict__ xt,
                                                    float* __restrict__ cp) {
  __shared__ __align__(16) float lds_a0[BM * BK];            // 16 KB
  __shared__ __align__(16) float lds_a1[BM * BK];            // 16 KB
  __shared__ __align__(16) unsigned short lds_b0[C96 * BK];  // 12 KB
  __shared__ __align__(16) unsigned short lds_b1[C96 * BK];  // 12 KB

  const int tid = threadIdx.x;
  const int wave = tid >> 6;
  const int lane = tid & 63;

  // Bijective XCD remap: 512 wgs round-robin XCDs by (wg&7); each XCD gets a
  // contiguous chunk so its 64 blocks share one split-K B panel in its L2.
  const int wg = blockIdx.x;
  const int swz = (wg & 7) * (512 / 8) + (wg >> 3);   // [0,512) bijective
  const int my = swz >> 8;                            // split-K index 0..1
  const int mx = swz & 255;                           // m-block 0..255
  const int m0 = mx * BM;
  const int kbase = my * KCHUNK;

  // staging source/dest (k0-invariant parts)
  const float* asrc[4];
  int adst[4];   // float offset within an A buffer (wave-uniform)
#pragma unroll
  for (int a = 0; a < 4; ++a) {
    int s = wave * 256 + a * 64 + lane;
    int row = s >> 4;
    int cu = (s & 15) ^ (row & 15);
    asrc[a] = L + (size_t)(m0 + row) * NN + kbase + cu * 4;
    adst[a] = (wave * 256 + a * 64) * 4;
  }
  const unsigned short* bsrc[3];
  int bdst[3];   // short offset within a B buffer (wave-uniform)
#pragma unroll
  for (int bi = 0; bi < 3; ++bi) {
    int s = wave * 192 + bi * 64 + lane;
    int c = s >> 3;
    int kg = (s & 7) ^ (c & 7);
    bsrc[bi] = xt + (size_t)c * NN + kbase + kg * 8;
    bdst[bi] = (wave * 192 + bi * 64) * 8;
  }

  // absolute LDS byte addresses for the asm fragment reads (iter-invariant)
  const int rowA = wave * 16 + (lane & 15);
  const int lq = lane >> 4;
  const unsigned baA0 = lds_off(lds_a0), baA1 = lds_off(lds_a1);
  const unsigned baB0 = lds_off(lds_b0), baB1 = lds_off(lds_b1);
  unsigned aAdr[2][2][2];   // [buf][kk][j]
  unsigned bAdr[2][2][6];   // [buf][kk][t]
#pragma unroll
  for (int kk = 0; kk < 2; ++kk) {
#pragma unroll
    for (int j = 0; j < 2; ++j) {
      int cu = (kk * 8 + lq * 2 + j) ^ (rowA & 15);
      unsigned off = (unsigned)(rowA * 16 + cu) * 16u;   // 16B slots
      aAdr[0][kk][j] = baA0 + off;
      aAdr[1][kk][j] = baA1 + off;
    }
#pragma unroll
    for (int t = 0; t < 6; ++t) {
      int c = t * 16 + (lane & 15);
      int kg = (kk * 4 + lq) ^ (c & 7);
      unsigned off = (unsigned)(c * 8 + kg) * 16u;       // 16B slots
      bAdr[0][kk][t] = baB0 + off;
      bAdr[1][kk][t] = baB1 + off;
    }
  }

  f32x4 acc[6];
#pragma unroll
  for (int t = 0; t < 6; ++t) acc[t] = (f32x4){0.f, 0.f, 0.f, 0.f};

  f32x4 av[2][2];
  short8 bv[2][6];

#define STAGE7(Abuf, Bbuf, ko)                                                   \
  do {                                                                           \
    _Pragma("unroll")                                                            \
    for (int a_ = 0; a_ < 4; ++a_)                                               \
      __builtin_amdgcn_global_load_lds((const as1_void*)(asrc[a_] + (ko)),       \
                                       (as3_void*)((Abuf) + adst[a_]), 16, 0, 0);\
    _Pragma("unroll")                                                            \
    for (int b_ = 0; b_ < 3; ++b_)                                               \
      __builtin_amdgcn_global_load_lds((const as1_void*)(bsrc[b_] + (ko)),       \
                                       (as3_void*)((Bbuf) + bdst[b_]), 16, 0, 0);\
  } while (0)

#define READ_TILE(BUF)                                                           \
  do {                                                                           \
    _Pragma("unroll")                                                            \
    for (int kk_ = 0; kk_ < 2; ++kk_) {                                          \
      av[kk_][0] = ds_read128f(aAdr[BUF][kk_][0]);                               \
      av[kk_][1] = ds_read128f(aAdr[BUF][kk_][1]);                               \
      _Pragma("unroll")                                                          \
      for (int t_ = 0; t_ < 6; ++t_)                                             \
        bv[kk_][t_] = ds_read128s(bAdr[BUF][kk_][t_]);                           \
    }                                                                            \
  } while (0)

#define COMPUTE()                                                                \
  do {                                                                           \
    _Pragma("unroll")                                                            \
    for (int kk_ = 0; kk_ < 2; ++kk_) {                                          \
      f32x4 a0_ = av[kk_][0], a1_ = av[kk_][1];                                  \
      short8 af_;                                                                \
      af_[0] = (short)f2bf(a0_[0]); af_[1] = (short)f2bf(a0_[1]);                \
      af_[2] = (short)f2bf(a0_[2]); af_[3] = (short)f2bf(a0_[3]);                \
      af_[4] = (short)f2bf(a1_[0]); af_[5] = (short)f2bf(a1_[1]);                \
      af_[6] = (short)f2bf(a1_[2]); af_[7] = (short)f2bf(a1_[3]);                \
      _Pragma("unroll")                                                          \
      for (int t_ = 0; t_ < 6; ++t_)                                             \
        acc[t_] = __builtin_amdgcn_mfma_f32_16x16x32_bf16(af_, bv[kk_][t_],      \
                                                          acc[t_], 0, 0, 0);     \
    }                                                                            \
  } while (0)

  // body for tile t living in buffer BUF: wait its 7 loads (7 newer stay in
  // flight), read fragments (asm), free the buffer, restage it for t+2, then
  // MFMA while 14 loads are in flight.
#define TILE_BODY(BUF, Abuf, Bbuf, nextko)                                       \
  do {                                                                           \
    asm volatile("s_waitcnt vmcnt(7)" ::: "memory");                             \
    __builtin_amdgcn_s_barrier();                                                \
    READ_TILE(BUF);                                                              \
    asm volatile("s_waitcnt lgkmcnt(0)" ::: "memory");                           \
    __builtin_amdgcn_sched_barrier(0);                                           \
    __builtin_amdgcn_s_barrier();                                                \
    STAGE7(Abuf, Bbuf, (nextko));                                                \
    __builtin_amdgcn_sched_barrier(0);                                           \
    COMPUTE();                                                                   \
  } while (0)

  // prologue: tiles 0 and 1 in flight (14 outstanding)
  STAGE7(lds_a0, lds_b0, 0);
  STAGE7(lds_a1, lds_b1, BK);

  // 63 pairs cover tiles 0..125, staging tiles 2..127
  for (int p = 0; p < (KITERS - 2) / 2; ++p) {
    const int t0 = 2 * p;
    TILE_BODY(0, lds_a0, lds_b0, (t0 + 2) * BK);
    TILE_BODY(1, lds_a1, lds_b1, (t0 + 3) * BK);
  }

  // tail: tile 126 (buf0), tile 127 (buf1) — no further staging
  {
    asm volatile("s_waitcnt vmcnt(7)" ::: "memory");
    __builtin_amdgcn_s_barrier();
    READ_TILE(0);
    asm volatile("s_waitcnt lgkmcnt(0)" ::: "memory");
    __builtin_amdgcn_sched_barrier(0);
    COMPUTE();

    asm volatile("s_waitcnt vmcnt(0)" ::: "memory");
    __builtin_amdgcn_s_barrier();
    READ_TILE(1);
    asm volatile("s_waitcnt lgkmcnt(0)" ::: "memory");
    __builtin_amdgcn_sched_barrier(0);
    COMPUTE();
  }

#undef TILE_BODY
#undef COMPUTE
#undef READ_TILE
#undef STAGE7

  // store split-K partial tile (each region written exactly once)
  float* cpd = cp + ((size_t)my * NN + m0) * C96;
#pragma unroll
  for (int t = 0; t < 6; ++t) {
    int col = t * 16 + (lane & 15);
#pragma unroll
    for (int r = 0; r < 4; ++r) {
      int row = wave * 16 + lq * 4 + r;
      cpd[(size_t)row * C96 + col] = acc[t][r];
    }
  }
}

// ---------------------------------------------------------------------------
// Epilogue: sum split-K partials, apply W[48x16] + bias, write out[2][N][16].
// ---------------------------------------------------------------------------
__global__ __launch_bounds__(256) void epilogue(const float* __restrict__ cp,
                                                const float* __restrict__ w,
                                                const float* __restrict__ bias,
                                                float* __restrict__ out) {
  __shared__ float lds_c[64 * 97];   // 64 nodes x 96 cols, +1 pad per row
  __shared__ float lds_w[48 * 16];
  __shared__ float lds_bias[16];
  const int tid = threadIdx.x;
  const int n0 = blockIdx.x * 64;

  for (int i = tid; i < 768; i += 256) lds_w[i] = w[i];
  if (tid < 16) lds_bias[tid] = bias[tid];

  const size_t base = (size_t)n0 * C96;
#pragma unroll
  for (int i = 0; i < 24; ++i) {
    int e = tid + i * 256;   // 0..6143 over [64 x 96]
    float s = 0.f;
#pragma unroll
    for (int sp = 0; sp < SPLITK; ++sp)
      s += cp[(size_t)sp * (NN * C96) + base + e];
    lds_c[e + e / 96] = s;   // node*97 + col
  }
  __syncthreads();

  const int node = tid >> 2;
  const int b = (tid >> 1) & 1;
  const int o0 = (tid & 1) * 8;
  const float* crow = &lds_c[node * 97 + b * 48];
  float accv[8];
#pragma unroll
  for (int o = 0; o < 8; ++o) accv[o] = lds_bias[o0 + o];
#pragma unroll
  for (int j = 0; j < 48; ++j) {
    float cv = crow[j];
#pragma unroll
    for (int o = 0; o < 8; ++o) accv[o] += cv * lds_w[j * 16 + o0 + o];
  }
  size_t ob = (size_t)b * (NN * OUTD) + (size_t)(n0 + node) * OUTD + o0;
  float4 v0 = {accv[0], accv[1], accv[2], accv[3]};
  float4 v1 = {accv[4], accv[5], accv[6], accv[7]};
  *(float4*)(out + ob) = v0;
  *(float4*)(out + ob + 4) = v1;
}

extern "C" void kernel_launch(void* const* d_in, const int* in_sizes, int n_in,
                              void* d_out, int out_size, void* d_ws, size_t ws_size,
                              hipStream_t stream) {
  (void)in_sizes; (void)n_in; (void)out_size; (void)ws_size;
  const float* inp = (const float*)d_in[0];   // [2,16384,32]
  const float* hid = (const float*)d_in[1];   // [2,16384*16]
  const float* lap = (const float*)d_in[2];   // [16384,16384]
  const float* wts = (const float*)d_in[3];   // [48,16]
  const float* bia = (const float*)d_in[4];   // [16]
  float* out = (float*)d_out;                 // [2,16384*16]

  unsigned short* xt = (unsigned short*)d_ws;                  // 3 MB bf16
  float* cp = (float*)((char*)d_ws + (4u << 20));              // 12.6 MB fp32

  prep_xt<<<NN / 64, 256, 0, stream>>>(inp, hid, xt);
  spmm_main<<<dim3(NN / BM * SPLITK), 256, 0, stream>>>(lap, xt, cp);
  epilogue<<<NN / 64, 256, 0, stream>>>(cp, wts, bia, out);
}